// Round 12
// baseline (4276.645 us; speedup 1.0000x reference)
//
#include <hip/hip_runtime.h>
#include <math.h>

typedef unsigned short u16;
typedef __attribute__((ext_vector_type(8))) short bf16x8;
typedef __attribute__((ext_vector_type(4))) float f32x4;

// ---- problem dims ----
static constexpr int D_S = 8192;
static constexpr int D_L = 4;
static constexpr int TOK = 65536;
static constexpr float NORMALIZER = 0.4204482076268573f;  // 32^-0.25
static constexpr float RATIO = 0.125f;                    // 64^-0.5
static constexpr float KEPS = 1e-4f;

// ---- workspace layout (float slots) ----
static constexpr size_t OFF_H     = 0;            // 16,777,216 fp32 residual
static constexpr size_t OFF_XNB   = 16777216;     // 8,388,608  bf16 xn [65536][256]
static constexpr size_t OFF_BIG   = 25165824;     // 16,777,216 bf16 xp/qp [65536][512] | FFN mid | xbf
static constexpr size_t OFF_V     = 41943040;     // 4,194,304  bf16 v/ao per-half [32768][256]
static constexpr size_t OFF_WKP   = 46137344;     // 131,072  single-plane [512][256]; embWt pre-loop
static constexpr size_t OFF_WQP   = 46268416;     // 131,072
static constexpr size_t OFF_WK    = 46399488;     // 65,536  (WQ contiguous -> combined [512][256] single)
static constexpr size_t OFF_WQ    = 46465024;     // 65,536
static constexpr size_t OFF_WV    = 46530560;     // 65,536
static constexpr size_t OFF_WO    = 46596096;     // 65,536
static constexpr size_t OFF_W1    = 46661632;     // 262,144 (single-plane uses half)
static constexpr size_t OFF_W2    = 46923776;     // 262,144
static constexpr size_t OFF_DG    = 47185920;     // 524,288 (bf16 [65536][16]: k-heads 0-7, q-heads 8-15)
static constexpr size_t OFF_KMAX  = 47710208;     // 64
static constexpr size_t OFF_PART  = 47710272;     // 2,097,152 ctx partials
static constexpr size_t OFF_PARTK = 49807424;     // 65,536
static constexpr size_t OFF_CTX   = 49872960;     // 131,072 (unused now, reserved)
static constexpr size_t OFF_KSUM  = 50004032;     // 4,096   (unused now, reserved)
static constexpr size_t OFF_POOL  = 50008128;     // 2,048
static constexpr size_t OFF_BT    = 50010176;     // 208,896 (u16 Bt[64][48][BTS])
static constexpr size_t NEED_BYTES = 200876288;   // <= 201,875,712 proven floor (round-2 probe)

static constexpr int BTS = 136;  // Bt row stride in u16 (128 + 8 pad)

static __device__ __forceinline__ float bf2f(u16 u) {
  return __uint_as_float(((unsigned int)u) << 16);
}
static __device__ __forceinline__ u16 f2bf(float f) {
  unsigned int u = __float_as_uint(f);
  u = (u + 0x7fffu + ((u >> 16) & 1u)) >> 16;
  return (u16)u;
}
static __device__ __forceinline__ float geluf(float v) {
  return 0.5f * v * (1.f + erff(v * 0.70710678118654752f));
}
static __device__ __forceinline__ float dec_max(unsigned int mk) {
  return __uint_as_float((mk & 0x80000000u) ? (mk & 0x7fffffffu) : ~mk);
}

__global__ void report_kernel(float* out, float v) {
  if (threadIdx.x < 16) out[threadIdx.x] = v;
}

__global__ __launch_bounds__(256) void zero_kernel(float* p, int n) {
  int i = blockIdx.x * 256 + threadIdx.x;
  if (i < n) p[i] = 0.f;
}

// ================= x -> bf16 =================
__global__ __launch_bounds__(256) void xcvt_kernel(const float* __restrict__ x,
                                                   u16* __restrict__ xb) {
  int i4 = (blockIdx.x * 256 + threadIdx.x) * 4;
  float4 v = *(const float4*)(x + i4);
  u16 o[4] = {f2bf(v.x), f2bf(v.y), f2bf(v.z), f2bf(v.w)};
  *(uint2*)(xb + i4) = *(uint2*)o;
}

// ================= layernorm: fp32 in, bf16 out =================
__global__ __launch_bounds__(256) void ln_kernel(
    const float* __restrict__ src, u16* __restrict__ dst,
    const float* __restrict__ g, const float* __restrict__ b) {
  int wv = threadIdx.x >> 6, lane = threadIdx.x & 63;
  int t = blockIdx.x * 4 + wv;
  const float4 v = *(const float4*)(src + (size_t)t * 256 + lane * 4);
  float s1 = v.x + v.y + v.z + v.w;
  float s2 = v.x * v.x + v.y * v.y + v.z * v.z + v.w * v.w;
  for (int off = 32; off; off >>= 1) {
    s1 += __shfl_xor(s1, off);
    s2 += __shfl_xor(s2, off);
  }
  float mu = s1 * (1.f / 256.f);
  float var = s2 * (1.f / 256.f) - mu * mu;
  float rs = rsqrtf(var + 1e-5f);
  float4 gg = *(const float4*)(g + lane * 4);
  float4 bb = *(const float4*)(b + lane * 4);
  u16 o0 = f2bf((v.x - mu) * rs * gg.x + bb.x);
  u16 o1 = f2bf((v.y - mu) * rs * gg.y + bb.y);
  u16 o2 = f2bf((v.z - mu) * rs * gg.z + bb.z);
  u16 o3 = f2bf((v.w - mu) * rs * gg.w + bb.w);
  uint2 pk;
  pk.x = (unsigned)o0 | ((unsigned)o1 << 16);
  pk.y = (unsigned)o2 | ((unsigned)o3 << 16);
  *(uint2*)(dst + (size_t)t * 256 + lane * 4) = pk;
}

// ===== embed weight, single-plane: [256 n][64 k] =====
__global__ __launch_bounds__(256) void wsplit1_kernel(
    const float* __restrict__ W, u16* __restrict__ Wt) {
  int i = blockIdx.x * 256 + threadIdx.x;   // 16384
  int k = i >> 8, n = i & 255;
  Wt[(size_t)n * 64 + k] = f2bf(W[i]);
}

// ===== merged per-layer weight prep (round-11 proven) =====
__global__ __launch_bounds__(256) void wprep_kernel(
    const float* __restrict__ wk, const float* __restrict__ wq,
    const float* __restrict__ wv, const float* __restrict__ wo,
    const float* __restrict__ w1, const float* __restrict__ w2,
    const float* __restrict__ proj,
    u16* __restrict__ WKP, u16* __restrict__ WQP,
    u16* __restrict__ WKt, u16* __restrict__ WQt,
    u16* __restrict__ WVt, u16* __restrict__ WOt,
    u16* __restrict__ W1t, u16* __restrict__ W2t,
    unsigned int* __restrict__ kmaxk) {
  int gi = blockIdx.x * 256 + threadIdx.x;
  if (gi < 64) kmaxk[gi] = 0u;
  if (gi < 262144) {  // WKP / WQP: proj-folded single-plane
    int i = gi & 131071;
    const float* w = (gi < 131072) ? wk : wq;
    u16* Wt = (gi < 131072) ? WKP : WQP;
    int k = i & 255, n = i >> 8;
    int head = n >> 6, m = n & 63;
    float s = 0.f;
#pragma unroll
    for (int d = 0; d < 32; ++d) s += w[k * 256 + head * 32 + d] * proj[m * 32 + d];
    Wt[(size_t)n * 256 + k] = f2bf(s * NORMALIZER);
  } else if (gi < 393216) {  // WKt / WQt single-plane
    int i = gi - 262144;
    const float* W = (i < 65536) ? wk : wq;
    u16* T = (i < 65536) ? WKt : WQt;
    int j = i & 65535;
    int k = j >> 8, n = j & 255;
    T[(size_t)n * 256 + k] = f2bf(W[j]);
  } else if (gi < 524288) {  // WVt / WOt hi/lo
    int i = gi - 393216;
    const float* W = (i < 65536) ? wv : wo;
    u16* T = (i < 65536) ? WVt : WOt;
    int j = i & 65535;
    int k = j >> 8, n = j & 255;
    float val = W[j];
    u16 hi = f2bf(val);
    u16 lo = f2bf(val - bf2f(hi));
    T[(size_t)n * 512 + k] = hi;
    T[(size_t)n * 512 + 256 + k] = lo;
  } else if (gi < 786432) {  // W1 single-plane: K=256, N=1024
    int i = gi - 524288;
    int k = i >> 10, n = i & 1023;
    W1t[(size_t)n * 256 + k] = f2bf(w1[i]);
  } else {                   // W2 single-plane: K=1024, N=256
    int i = gi - 786432;
    int k = i >> 8, n = i & 255;
    W2t[(size_t)n * 1024 + k] = f2bf(w2[i]);
  }
}

// ================= MFMA GEMM: 128x128 tile, BK=64, A bf16 [M][K], Wt bf16 [N][K*KM] =================
// KM=2: hi/lo split weights; KM=1: single-plane.
// EPI: 0 plain (ACT gelu, ACC fp32-acc, OBF bf16 store), 3 qp, 4 embed,
//      6 fused xp(y<4: store+max over Wt)+diag(y>=4: over Wt2)
template <int EPI, int ACT, int ACC, int OBF, int KM>
__global__ __launch_bounds__(256) void mfma_gemm(
    const u16* __restrict__ A, const u16* __restrict__ Wt,
    const u16* __restrict__ Wt2,
    const float* __restrict__ bias, const float* __restrict__ posP,
    const u16* __restrict__ diagIn,
    float* __restrict__ outF, u16* __restrict__ outB,
    u16* __restrict__ diagOut, unsigned int* __restrict__ kmaxOut,
    int N, int K) {
  __shared__ __align__(16) u16 Als[8192];   // [q0 0..7][row 0..127] x 8 u16 = 16KB
  __shared__ __align__(16) u16 Bls[8192];
  const int K2 = K * KM;
  int tid = threadIdx.x;
  int yb = blockIdx.y;
  int bm = blockIdx.x * 128;
  const u16* Wp = Wt;
  int bn = yb * 128;
  if (EPI == 6 && yb >= 4) { Wp = Wt2; bn = (yb - 4) * 128; }
  int w = tid >> 6, lane = tid & 63;
  int wm = w >> 1, wn = w & 1;
  int lr = lane & 15, lq = lane >> 4;
  f32x4 acc[4][4];
#pragma unroll
  for (int i = 0; i < 4; ++i)
#pragma unroll
    for (int j = 0; j < 4; ++j) acc[i][j] = (f32x4){0.f, 0.f, 0.f, 0.f};
  int r0 = tid >> 3, q0 = tid & 7;          // 32 rows per pass, 8 k-chunks of 8
  for (int k0 = 0; k0 < K2; k0 += 64) {
    int kk = k0 + q0 * 8;
    int gka = kk & (K - 1);
    uint4 av[4], bv[4];
#pragma unroll
    for (int u = 0; u < 4; ++u) {
      int row = r0 + u * 32;
      av[u] = *(const uint4*)(A + (size_t)(bm + row) * K + gka);
      bv[u] = *(const uint4*)(Wp + (size_t)(bn + row) * K2 + kk);
    }
    __syncthreads();
#pragma unroll
    for (int u = 0; u < 4; ++u) {
      int row = r0 + u * 32;
      ((uint4*)Als)[q0 * 128 + row] = av[u];
      ((uint4*)Bls)[q0 * 128 + row] = bv[u];
    }
    __syncthreads();
#pragma unroll
    for (int s = 0; s < 2; ++s) {
      bf16x8 af[4], bfr[4];
#pragma unroll
      for (int mi = 0; mi < 4; ++mi)
        af[mi] = ((const bf16x8*)Als)[(s * 4 + lq) * 128 + wm * 64 + mi * 16 + lr];
#pragma unroll
      for (int ni = 0; ni < 4; ++ni)
        bfr[ni] = ((const bf16x8*)Bls)[(s * 4 + lq) * 128 + wn * 64 + ni * 16 + lr];
#pragma unroll
      for (int mi = 0; mi < 4; ++mi)
#pragma unroll
        for (int ni = 0; ni < 4; ++ni)
          acc[mi][ni] = __builtin_amdgcn_mfma_f32_16x16x32_bf16(af[mi], bfr[ni], acc[mi][ni], 0, 0, 0);
    }
  }
  // ---- epilogues ----  C/D: col = lane&15, row = (lane>>4)*4 + r  [m89-verified]
  if (EPI == 0) {
#pragma unroll
    for (int ni = 0; ni < 4; ++ni) {
      int col = bn + wn * 64 + ni * 16 + lr;
      float bv2 = bias ? bias[col] : 0.f;
#pragma unroll
      for (int mi = 0; mi < 4; ++mi)
#pragma unroll
        for (int r = 0; r < 4; ++r) {
          int rowg = bm + wm * 64 + mi * 16 + lq * 4 + r;
          float val = acc[mi][ni][r] + bv2;
          if (ACT) val = geluf(val);
          size_t o = (size_t)rowg * N + col;
          if (OBF) outB[o] = f2bf(val);
          else if (ACC) outF[o] += val;
          else outF[o] = val;
        }
    }
  }
  if (EPI == 3) {  // qp: in-wave row-max over the head's 64 cols, then exp; dg q-heads at +8
    int head = (bn + wn * 64) >> 6;
#pragma unroll
    for (int mi = 0; mi < 4; ++mi) {
      float rm[4] = {-3.4e38f, -3.4e38f, -3.4e38f, -3.4e38f};
#pragma unroll
      for (int ni = 0; ni < 4; ++ni)
#pragma unroll
        for (int r = 0; r < 4; ++r) rm[r] = fmaxf(rm[r], acc[mi][ni][r]);
#pragma unroll
      for (int r = 0; r < 4; ++r) {
        float t = rm[r];
        t = fmaxf(t, __shfl_xor(t, 1)); t = fmaxf(t, __shfl_xor(t, 2));
        t = fmaxf(t, __shfl_xor(t, 4)); t = fmaxf(t, __shfl_xor(t, 8));
        rm[r] = t;
      }
#pragma unroll
      for (int r = 0; r < 4; ++r) {
        int rowg = bm + wm * 64 + mi * 16 + lq * 4 + r;
        float dg = bf2f(diagIn[(size_t)rowg * 16 + 8 + head]);
#pragma unroll
        for (int ni = 0; ni < 4; ++ni) {
          int col = bn + wn * 64 + ni * 16 + lr;
          float v = RATIO * (__expf(acc[mi][ni][r] - dg - rm[r]) + KEPS);
          outB[(size_t)rowg * N + col] = f2bf(v);
        }
      }
    }
  }
  if (EPI == 4) {  // embed: + bias + pos, fp32 store (N==256)
#pragma unroll
    for (int ni = 0; ni < 4; ++ni) {
      int col = bn + wn * 64 + ni * 16 + lr;
      float bv2 = bias[col];
#pragma unroll
      for (int mi = 0; mi < 4; ++mi)
#pragma unroll
        for (int r = 0; r < 4; ++r) {
          int rowg = bm + wm * 64 + mi * 16 + lq * 4 + r;
          outF[(size_t)rowg * 256 + col] =
              acc[mi][ni][r] + bv2 + posP[(size_t)(rowg & (D_S - 1)) * 256 + col];
        }
    }
  }
  if (EPI == 6) {
    if (yb < 4) {  // xp: store bf16 + global max per (b, head)
      float mx = -3.4e38f;
#pragma unroll
      for (int mi = 0; mi < 4; ++mi)
#pragma unroll
        for (int ni = 0; ni < 4; ++ni)
#pragma unroll
          for (int r = 0; r < 4; ++r) {
            float v = acc[mi][ni][r];
            mx = fmaxf(mx, v);
            int rowg = bm + wm * 64 + mi * 16 + lq * 4 + r;
            int col = bn + wn * 64 + ni * 16 + lr;
            outB[(size_t)rowg * N + col] = f2bf(v);
          }
#pragma unroll
      for (int off = 1; off < 64; off <<= 1) mx = fmaxf(mx, __shfl_xor(mx, off));
      if (lane == 0) {
        int b = bm >> 13;
        int head = (bn + wn * 64) >> 6;
        unsigned int u = __float_as_uint(mx);
        unsigned int key = (u & 0x80000000u) ? ~u : (u | 0x80000000u);
        atomicMax(kmaxOut + b * 8 + head, key);
      }
    } else {  // diag per head (32 cols); wave spans 2 heads; dg layout [t][16]
      const float c05n2 = 0.5f * NORMALIZER * NORMALIZER;
      int hb = (bn + wn * 64) >> 5;
#pragma unroll
      for (int mi = 0; mi < 4; ++mi) {
        float s0[4] = {0.f, 0.f, 0.f, 0.f}, s1[4] = {0.f, 0.f, 0.f, 0.f};
#pragma unroll
        for (int ni = 0; ni < 4; ++ni)
#pragma unroll
          for (int r = 0; r < 4; ++r) {
            float v = acc[mi][ni][r];
            if (ni < 2) s0[r] += v * v; else s1[r] += v * v;
          }
#pragma unroll
        for (int r = 0; r < 4; ++r) {
          float a = s0[r], b = s1[r];
          a += __shfl_xor(a, 1); a += __shfl_xor(a, 2); a += __shfl_xor(a, 4); a += __shfl_xor(a, 8);
          b += __shfl_xor(b, 1); b += __shfl_xor(b, 2); b += __shfl_xor(b, 4); b += __shfl_xor(b, 8);
          if (lr == 0) {
            int rowg = bm + wm * 64 + mi * 16 + lq * 4 + r;
            diagOut[(size_t)rowg * 16 + hb] = f2bf(c05n2 * a);
            diagOut[(size_t)rowg * 16 + hb + 1] = f2bf(c05n2 * b);
          }
        }
      }
    }
  }
}

// ===== ctxaccum: kp computed inline from raw xp (exp fused); part[m][e] = sum kp*v =====
__global__ __launch_bounds__(256) void ctxaccum_kernel(
    const u16* __restrict__ xp, const u16* __restrict__ v,
    const u16* __restrict__ dg, const unsigned int* __restrict__ kmaxk,
    float* __restrict__ part, float* __restrict__ partk, int hf) {
  __shared__ float kpS[64 * 64];
  __shared__ float vS[64 * 32];
  int tid = threadIdx.x;
  int bl = blockIdx.x >> 3, head = blockIdx.x & 7, c = blockIdx.y;
  int n0l = bl * 8192 + c * 512;   // within half (32768 tokens)
  int bhg = (hf * 4 + bl) * 8 + head;
  int tg0 = hf * 32768 + n0l;
  float mx = dec_max(kmaxk[bhg]);
  int m = tid & 63, eg = tid >> 6;
  float acc[8] = {};
  float ks = 0.f;
  const u16* kpb = xp + (size_t)tg0 * 512 + head * 64;
  const u16* vb = v + (size_t)n0l * 256 + head * 32;
  for (int tile = 0; tile < 8; ++tile) {
    int nb = tile * 64;
    __syncthreads();
#pragma unroll
    for (int i = 0; i < 2; ++i) {
      int idx8 = tid + i * 256;
      int row = idx8 >> 3, c8 = (idx8 & 7) * 8;
      float dgrow = bf2f(dg[(size_t)(tg0 + nb + row) * 16 + head]);
      u16 tmp[8];
      *(uint4*)tmp = *(const uint4*)(kpb + (size_t)(nb + row) * 512 + c8);
#pragma unroll
      for (int j = 0; j < 8; ++j)
        kpS[row * 64 + c8 + j] = RATIO * (__expf(bf2f(tmp[j]) - dgrow - mx) + KEPS);
    }
    {
      int row = tid >> 2, c8 = (tid & 3) * 8;
      u16 tmp[8];
      *(uint4*)tmp = *(const uint4*)(vb + (size_t)(nb + row) * 256 + c8);
#pragma unroll
      for (int j = 0; j < 8; ++j) vS[row * 32 + c8 + j] = bf2f(tmp[j]);
    }
    __syncthreads();
#pragma unroll 4
    for (int n = 0; n < 64; ++n) {
      float kv = kpS[n * 64 + m];
      if (eg == 0) ks += kv;
      const float* vr = &vS[n * 32 + eg * 8];
#pragma unroll
      for (int j = 0; j < 8; ++j) acc[j] += kv * vr[j];
    }
  }
  float* pp = part + ((size_t)bhg * 16 + c) * 2048 + m * 32 + eg * 8;
#pragma unroll
  for (int j = 0; j < 8; ++j) pp[j] = acc[j];
  if (eg == 0) partk[((size_t)bhg * 16 + c) * 64 + m] = ks;
}

// ===== ctxreduce + btprep merged: reduce partials and write Bt directly =====
// Bt lives in its own region (OFF_BT) - no overlap with part.
__global__ __launch_bounds__(256) void ctxreduce_kernel(
    const float* __restrict__ part, const float* __restrict__ partk,
    u16* __restrict__ Bt) {
  int bh = blockIdx.x, tid = threadIdx.x;
#pragma unroll
  for (int i = 0; i < 8; ++i) {
    int idx = tid + i * 256;           // = m*32 + e
    float s = 0.f;
#pragma unroll
    for (int cc = 0; cc < 16; ++cc)
      s += part[((size_t)bh * 16 + cc) * 2048 + idx];
    int e = idx & 31, m = idx >> 5;
    u16 hi = f2bf(s);
    u16 lo = f2bf(s - bf2f(hi));
    u16* row = Bt + ((size_t)bh * 48 + e) * BTS;
    row[m] = hi;
    row[64 + m] = lo;
  }
  if (tid < 64) {
    float s = 0.f;
#pragma unroll
    for (int cc = 0; cc < 16; ++cc) s += partk[((size_t)bh * 16 + cc) * 64 + tid];
    u16 hi = f2bf(s);
    u16 lo = f2bf(s - bf2f(hi));
    u16* row = Bt + ((size_t)bh * 48 + 32) * BTS;
    row[tid] = hi;
    row[64 + tid] = lo;
  }
  for (int z = tid; z < 15 * 128; z += 256) {  // zero rows 33..47
    int n = 33 + (z >> 7), k = z & 127;
    Bt[((size_t)bh * 48 + n) * BTS + k] = 0;
  }
}

// ===== attnout via MFMA: ao = (qp@ctx)/(qp@ksum) =====
__global__ __launch_bounds__(256) void attnout_kernel(
    const u16* __restrict__ qp, const u16* __restrict__ Bt,
    u16* __restrict__ ao, int hf) {
  __shared__ __align__(16) u16 BtS[48 * BTS];
  int tid = threadIdx.x;
  int rb = blockIdx.x, head = blockIdx.y;
  int t0l = rb * 128;
  int bhg = ((hf * 32768 + t0l) >> 13) * 8 + head;
  {
    const uint4* src = (const uint4*)(Bt + (size_t)bhg * 48 * BTS);
    for (int i = tid; i < 48 * BTS / 8; i += 256) ((uint4*)BtS)[i] = src[i];
  }
  __syncthreads();
  int w = tid >> 6, lane = tid & 63;
  int lr = lane & 15, lq = lane >> 4;
  int tw = t0l + w * 32;
  const u16* qpb = qp + (size_t)(hf * 32768 + tw) * 512 + head * 64;
  bf16x8 af[2][2];
#pragma unroll
  for (int mt = 0; mt < 2; ++mt)
#pragma unroll
    for (int kc = 0; kc < 2; ++kc)
      af[mt][kc] = *(const bf16x8*)(qpb + (size_t)(mt * 16 + lr) * 512 + kc * 32 + lq * 8);
  f32x4 c0[2], c1[2], c2[2];
#pragma unroll
  for (int mt = 0; mt < 2; ++mt) {
    c0[mt] = (f32x4){0.f, 0.f, 0.f, 0.f};
    c1[mt] = (f32x4){0.f, 0.f, 0.f, 0.f};
    c2[mt] = (f32x4){0.f, 0.f, 0.f, 0.f};
  }
#pragma unroll
  for (int kc = 0; kc < 4; ++kc) {
    bf16x8 b0 = *(const bf16x8*)(BtS + (size_t)(0 * 16 + lr) * BTS + kc * 32 + lq * 8);
    bf16x8 b1 = *(const bf16x8*)(BtS + (size_t)(1 * 16 + lr) * BTS + kc * 32 + lq * 8);
    bf16x8 b2 = *(const bf16x8*)(BtS + (size_t)(2 * 16 + lr) * BTS + kc * 32 + lq * 8);
#pragma unroll
    for (int mt = 0; mt < 2; ++mt) {
      bf16x8 a = af[mt][kc & 1];
      c0[mt] = __builtin_amdgcn_mfma_f32_16x16x32_bf16(a, b0, c0[mt], 0, 0, 0);
      c1[mt] = __builtin_amdgcn_mfma_f32_16x16x32_bf16(a, b1, c1[mt], 0, 0, 0);
      c2[mt] = __builtin_amdgcn_mfma_f32_16x16x32_bf16(a, b2, c2[mt], 0, 0, 0);
    }
  }
#pragma unroll
  for (int mt = 0; mt < 2; ++mt)
#pragma unroll
    for (int r = 0; r < 4; ++r) {
      float den = __shfl(c2[mt][r], lane & 48);
      int rowl = tw + mt * 16 + lq * 4 + r;
      float inv = 1.f / den;
      ao[(size_t)rowl * 256 + head * 32 + lr] = f2bf(c0[mt][r] * inv);
      ao[(size_t)rowl * 256 + head * 32 + 16 + lr] = f2bf(c1[mt][r] * inv);
    }
}

// ================= mean pool + final FC (fp32 h) =================
__global__ __launch_bounds__(256) void pool_kernel(
    const float* __restrict__ h, float* __restrict__ pooled) {
  int b = blockIdx.x, chunk = blockIdx.y, j = threadIdx.x;
  const float* hp = h + (size_t)(b * D_S + chunk * 256) * 256 + j;
  float acc = 0.f;
#pragma unroll 4
  for (int s = 0; s < 256; ++s) acc += hp[(size_t)s * 256];
  atomicAdd(pooled + b * 256 + j, acc);
}

__global__ __launch_bounds__(64) void final_kernel(
    const float* __restrict__ pooled, const float* __restrict__ fcw,
    const float* __restrict__ fcb, float* __restrict__ out) {
  int tid = threadIdx.x;
  if (tid >= 16) return;
  int b = tid >> 1, c = tid & 1;
  float acc = 0.f;
  for (int j = 0; j < 256; ++j) acc += pooled[b * 256 + j] * fcw[j * 2 + c];
  out[b * 2 + c] = acc * (1.f / 8192.f) + fcb[c];
}

extern "C" void kernel_launch(void* const* d_in, const int* in_sizes, int n_in,
                              void* d_out, int out_size, void* d_ws, size_t ws_size,
                              hipStream_t stream) {
  const float* x     = (const float*)d_in[0];
  const float* emb_w = (const float*)d_in[1];
  const float* emb_b = (const float*)d_in[2];
  const float* pos   = (const float*)d_in[3];
  const float* ln1_g = (const float*)d_in[4];
  const float* ln1_b = (const float*)d_in[5];
  const float* wq    = (const float*)d_in[6];
  const float* wk    = (const float*)d_in[7];
  const float* wv    = (const float*)d_in[8];
  const float* wo    = (const float*)d_in[9];
  const float* bo    = (const float*)d_in[10];
  const float* ln2_g = (const float*)d_in[11];
  const float* ln2_b = (const float*)d_in[12];
  const float* w1    = (const float*)d_in[13];
  const float* b1    = (const float*)d_in[14];
  const float* w2    = (const float*)d_in[15];
  const float* b2    = (const float*)d_in[16];
  const float* proj  = (const float*)d_in[17];
  const float* fc_w  = (const float*)d_in[18];
  const float* fc_b  = (const float*)d_in[19];

  if (ws_size < NEED_BYTES) {
    report_kernel<<<1, 64, 0, stream>>>((float*)d_out, (float)ws_size);
    return;
  }

  float* ws = (float*)d_ws;
  float* h      = ws + OFF_H;
  u16* xnb      = (u16*)(ws + OFF_XNB);
  u16* BIG      = (u16*)(ws + OFF_BIG);
  u16* Vb       = (u16*)(ws + OFF_V);
  u16* WKPt     = (u16*)(ws + OFF_WKP);
  u16* WQPt     = (u16*)(ws + OFF_WQP);
  u16* WKt      = (u16*)(ws + OFF_WK);
  u16* WQt      = (u16*)(ws + OFF_WQ);
  u16* WVt      = (u16*)(ws + OFF_WV);
  u16* WOt      = (u16*)(ws + OFF_WO);
  u16* W1t      = (u16*)(ws + OFF_W1);
  u16* W2t      = (u16*)(ws + OFF_W2);
  u16* dg       = (u16*)(ws + OFF_DG);
  unsigned int* kmaxk = (unsigned int*)(ws + OFF_KMAX);
  float* part   = ws + OFF_PART;
  float* partk  = ws + OFF_PARTK;
  u16* Bt       = (u16*)(ws + OFF_BT);
  float* pooled = ws + OFF_POOL;

  // ---- embed as MFMA GEMM (single-plane weights) ----
  xcvt_kernel<<<4096, 256, 0, stream>>>(x, BIG);
  wsplit1_kernel<<<64, 256, 0, stream>>>(emb_w, WKPt);
  mfma_gemm<4, 0, 0, 0, 1><<<dim3(512, 2), 256, 0, stream>>>(
      BIG, WKPt, nullptr, emb_b, pos, nullptr, h, nullptr, nullptr, nullptr, 256, 64);

  for (int l = 0; l < D_L; ++l) {
    const float* pj = proj + l * 2048;
    ln_kernel<<<TOK / 4, 256, 0, stream>>>(h, xnb, ln1_g + l * 256, ln1_b + l * 256);
    wprep_kernel<<<4096, 256, 0, stream>>>(
        wk + l * 65536, wq + l * 65536, wv + l * 65536, wo + l * 65536,
        w1 + l * 262144, w2 + l * 262144, pj,
        WKPt, WQPt, WKt, WQt, WVt, WOt, W1t, W2t, kmaxk);

    // fused xp(+kmax) and diag(k|q): one launch, y<4 xp / y>=4 diag
    mfma_gemm<6, 0, 0, 1, 1><<<dim3(512, 8), 256, 0, stream>>>(
        xnb, WKPt, WKt, nullptr, nullptr, nullptr, nullptr, BIG, dg, kmaxk, 512, 256);
    // context accumulation per half (exp fused into staging)
    for (int hf = 0; hf < 2; ++hf) {
      const u16* xh = xnb + (size_t)hf * 32768 * 256;
      mfma_gemm<0, 0, 0, 1, 2><<<dim3(256, 2), 256, 0, stream>>>(
          xh, WVt, nullptr, nullptr, nullptr, nullptr, nullptr, Vb, nullptr, nullptr, 256, 256);
      ctxaccum_kernel<<<dim3(32, 16), 256, 0, stream>>>(BIG, Vb, dg, kmaxk, part, partk, hf);
    }
    ctxreduce_kernel<<<64, 256, 0, stream>>>(part, partk, Bt);
    // qp (overwrites BIG; xp dead), single-plane WQP
    mfma_gemm<3, 0, 0, 1, 1><<<dim3(512, 4), 256, 0, stream>>>(
        xnb, WQPt, nullptr, nullptr, nullptr, dg, nullptr, BIG, nullptr, nullptr, 512, 256);
    for (int hf = 0; hf < 2; ++hf) {
      float* hh = h + (size_t)hf * 32768 * 256;
      attnout_kernel<<<dim3(256, 8), 256, 0, stream>>>(BIG, Bt, Vb, hf);
      mfma_gemm<0, 0, 1, 0, 2><<<dim3(256, 2), 256, 0, stream>>>(
          Vb, WOt, nullptr, bo + l * 256, nullptr, nullptr, hh, nullptr, nullptr, nullptr, 256, 256);
    }

    ln_kernel<<<TOK / 4, 256, 0, stream>>>(h, xnb, ln2_g + l * 256, ln2_b + l * 256);
    for (int hf = 0; hf < 2; ++hf) {
      const u16* xh = xnb + (size_t)hf * 32768 * 256;
      float* hh = h + (size_t)hf * 32768 * 256;
      mfma_gemm<0, 1, 0, 1, 1><<<dim3(256, 8), 256, 0, stream>>>(
          xh, W1t, nullptr, b1 + l * 1024, nullptr, nullptr, nullptr, BIG, nullptr, nullptr, 1024, 256);
      mfma_gemm<0, 0, 1, 0, 1><<<dim3(256, 2), 256, 0, stream>>>(
          BIG, W2t, nullptr, b2 + l * 256, nullptr, nullptr, hh, nullptr, nullptr, nullptr, 256, 1024);
    }
  }

  zero_kernel<<<8, 256, 0, stream>>>(pooled, 2048);
  pool_kernel<<<dim3(8, 32), 256, 0, stream>>>(h, pooled);
  final_kernel<<<1, 64, 0, stream>>>(pooled, fc_w, fc_b, (float*)d_out);
}